// Round 10
// baseline (1567.009 us; speedup 1.0000x reference)
//
#include <hip/hip_runtime.h>
#include <hip/hip_bf16.h>

#define N_NODES 100000
#define N_EDGES 1200000
#define N_GRAPH 1000
#define F_INN   7
#define HDIM    64
#define GFEAT   10
#define T_OUT   5
#define EPSF    1e-5f

// flags: [0]=edge wide(int64) [1]=batch wide [2]=1D fp32 [3]=world fp32
// [4]=dtype disagreement [8]=deg sum ok [9]=cnt sum ok [10]=batch sorted

__device__ __forceinline__ float ldf(const void* p, int i, int isf32) {
    return isf32 ? ((const float*)p)[i]
                 : __bfloat162float(((const __hip_bfloat16*)p)[i]);
}
// LAYOUT L1: first half = src, second half = dst (natural (2,E) row-major)
__device__ __forceinline__ int ld_src(const int* edge, int e, int wide) {
    return wide ? edge[2 * e] : edge[e];
}
__device__ __forceinline__ int ld_dst(const int* edge, int e, int wide) {
    return wide ? edge[2 * (N_EDGES + e)] : edge[N_EDGES + e];
}
__device__ __forceinline__ int ld_batch(const int* batch, int v, int wide) {
    return wide ? batch[2 * v] : batch[v];
}

__global__ void SimpleGCN_6640019440134_kernel() {}

// fp32 output fills (d_out is float*: reference output dtype is float32)
__global__ void sgcn10_fill(float* out, int n, float val) {
    int i = blockIdx.x * blockDim.x + threadIdx.x;
    if (i < n) out[i] = val;
}

__global__ void __launch_bounds__(256) sgcn10_probe(const int* edge, const int* batch,
                                                    const unsigned* g1,
                                                    const unsigned short* x,
                                                    const unsigned short* W1,
                                                    const unsigned short* W2,
                                                    int* flags) {
    __shared__ int sh[8];
    int t = threadIdx.x;
    if (t < 8) sh[t] = 0;
    __syncthreads();
    {
        int pos = 1 + 2 * 4687 * t;               // odd words across first 2E words
        if (edge[pos] != 0) atomicOr(&sh[0], 1);
    }
    {
        int pos = (N_NODES - 511) + 2 * t;        // odd words at tail of first N words
        if (batch[pos] != 0) atomicOr(&sh[1], 1);
    }
    if (t < 16 && g1[t] != 0x3F800000u) atomicOr(&sh[2], 1);
    {
        int e = (x[t] >> 7) & 0xFF;  if (e >= 100 && e <= 140) atomicAdd(&sh[3], 1);
        e = (W1[t] >> 7) & 0xFF;     if (e >= 100 && e <= 140) atomicAdd(&sh[4], 1);
        e = (W2[t] >> 7) & 0xFF;     if (e >= 100 && e <= 140) atomicAdd(&sh[5], 1);
    }
    __syncthreads();
    if (t == 0) {
        flags[0] = (sh[0] == 0);
        flags[1] = (sh[1] == 0);
        flags[2] = (sh[2] == 0);
        int fx = (sh[3] < 192), fw1 = (sh[4] < 192), fw2 = (sh[5] < 192);
        flags[3] = (fx + fw1 + fw2 >= 2);
        flags[4] = !(fx == fw1 && fw1 == fw2);
    }
}

__global__ void sgcn10_zero(float* zbuf, int zcount) {
    int i = blockIdx.x * blockDim.x + threadIdx.x;
    if (i < zcount) zbuf[i] = 0.f;
}

__global__ void sgcn10_vsort(const int* __restrict__ batch, int* flags,
                             const int* __restrict__ fl) {
    int wide = fl[1];
    int v = blockIdx.x * blockDim.x + threadIdx.x;
    if (v == 0) flags[10] = 1;
    if (v < N_NODES - 1) {
        if (ld_batch(batch, v, wide) > ld_batch(batch, v + 1, wide))
            atomicAnd(&flags[10], 0);
    }
}

__global__ void sgcn10_deg(const int* __restrict__ edge, float* deg, const int* __restrict__ fl) {
    int wide = fl[0];
    int e = blockIdx.x * blockDim.x + threadIdx.x;
    if (e < N_EDGES) {
        unsigned d = (unsigned)ld_dst(edge, e, wide);
        if (d < N_NODES) atomicAdd(&deg[d], 1.0f);
    }
}

__global__ void __launch_bounds__(256) sgcn10_vdeg(const float* deg, int* flags) {
    __shared__ float sd[256];
    float s = 0.f;
    for (int v = threadIdx.x; v < N_NODES; v += 256) s += deg[v];
    sd[threadIdx.x] = s;
    __syncthreads();
    for (int o = 128; o > 0; o >>= 1) {
        if (threadIdx.x < o) sd[threadIdx.x] += sd[threadIdx.x + o];
        __syncthreads();
    }
    if (threadIdx.x == 0) flags[8] = (sd[0] == (float)N_EDGES);
}

__global__ void sgcn10_dis_cnt(float* dis, const int* __restrict__ batch, float* cnts,
                               const int* __restrict__ fl) {
    int wide = fl[1];
    int v = blockIdx.x * blockDim.x + threadIdx.x;
    if (v < N_NODES) {
        dis[v] = rsqrtf(dis[v] + 1.0f);   // deg includes self loop
        unsigned g = (unsigned)ld_batch(batch, v, wide);
        if (g < N_GRAPH) atomicAdd(&cnts[g], 1.0f);
    }
}

__global__ void __launch_bounds__(256) sgcn10_vcnt(const float* cnts, int* flags) {
    __shared__ float sd[256];
    float s = 0.f;
    for (int g = threadIdx.x; g < N_GRAPH; g += 256) s += cnts[g];
    sd[threadIdx.x] = s;
    __syncthreads();
    for (int o = 128; o > 0; o >>= 1) {
        if (threadIdx.x < o) sd[threadIdx.x] += sd[threadIdx.x + o];
        __syncthreads();
    }
    if (threadIdx.x == 0) flags[9] = (sd[0] == (float)N_NODES);
}

// bufA[v] = x[v] @ W1
__global__ void __launch_bounds__(256) sgcn10_l1(const void* x, const void* W1,
                                                 float* __restrict__ bufA,
                                                 const int* __restrict__ fl) {
    int fw = fl[3];
    __shared__ float w[F_INN][HDIM];
    int t = threadIdx.x;
    for (int i = t; i < F_INN * HDIM; i += 256) w[i / HDIM][i % HDIM] = ldf(W1, i, fw);
    __syncthreads();
    int lane = t & 63, sub = t >> 6;
    for (int v = blockIdx.x * 4 + sub; v < N_NODES; v += gridDim.x * 4) {
        float acc = 0.f;
#pragma unroll
        for (int k = 0; k < F_INN; k++) acc += ldf(x, v * F_INN + k, fw) * w[k][lane];
        bufA[v * HDIM + lane] = acc;
    }
}

// bufB[v] = bufA[v] * dis[v]^2   (self loop)
__global__ void __launch_bounds__(256) sgcn10_self(const float* __restrict__ bufA,
                                                   const float* __restrict__ dis,
                                                   float* __restrict__ bufB) {
    int idx = blockIdx.x * blockDim.x + threadIdx.x;
    int v = idx >> 6, lane = idx & 63;
    if (v < N_NODES) {
        float d = dis[v];
        bufB[v * HDIM + lane] = bufA[v * HDIM + lane] * d * d;
    }
}

// bufB[d] += bufA[s] * dis[s]*dis[d]
__global__ void __launch_bounds__(256) sgcn10_scatter(const int* __restrict__ edge,
                                                      const float* __restrict__ bufA,
                                                      const float* __restrict__ dis,
                                                      float* __restrict__ bufB,
                                                      const int* __restrict__ fl) {
    int wide = fl[0];
    int idx = blockIdx.x * blockDim.x + threadIdx.x;
    int e = idx >> 6, lane = idx & 63;
    if (e < N_EDGES) {
        unsigned s = (unsigned)ld_src(edge, e, wide);
        unsigned d = (unsigned)ld_dst(edge, e, wide);
        if (s < N_NODES && d < N_NODES) {
            float nrm = dis[s] * dis[d];
            atomicAdd(&bufB[d * HDIM + lane], bufA[s * HDIM + lane] * nrm);
        }
    }
}

__global__ void __launch_bounds__(256) sgcn10_finish_bn(float* bufB, const void* b,
                                                        float* sums, float* sumsq,
                                                        const int* __restrict__ fl) {
    int f1d = fl[2];
    __shared__ float shs[4][HDIM], shs2[4][HDIM];
    int lane = threadIdx.x & 63, w = threadIdx.x >> 6;
    float bb = ldf(b, lane, f1d);
    float s = 0.f, s2 = 0.f;
    for (int v = blockIdx.x * 4 + w; v < N_NODES; v += gridDim.x * 4) {
        float val = bufB[v * HDIM + lane] + bb;
        bufB[v * HDIM + lane] = val;
        s += val; s2 += val * val;
    }
    shs[w][lane] = s; shs2[w][lane] = s2;
    __syncthreads();
    if (w == 0) {
        float ts  = shs[0][lane] + shs[1][lane] + shs[2][lane] + shs[3][lane];
        float ts2 = shs2[0][lane] + shs2[1][lane] + shs2[2][lane] + shs2[3][lane];
        atomicAdd(&sums[lane], ts);
        atomicAdd(&sumsq[lane], ts2);
    }
}

__global__ void sgcn10_bn_final(float* sums, float* sumsq, const void* gamma, const void* beta,
                                float* scale, float* shift, const int* __restrict__ fl) {
    int f1d = fl[2];
    int j = threadIdx.x;
    float mean = sums[j] / (float)N_NODES;
    float var  = sumsq[j] / (float)N_NODES - mean * mean;
    float sc = ldf(gamma, j, f1d) * rsqrtf(var + EPSF);
    scale[j] = sc;
    shift[j] = ldf(beta, j, f1d) - mean * sc;
    sums[j] = 0.f; sumsq[j] = 0.f;
}

// bufA[v] = relu(bufB[v]*sc+sh) @ W
__global__ void __launch_bounds__(256) sgcn10_l23(const float* __restrict__ bufB, const void* W,
                                                  const float* __restrict__ scale,
                                                  const float* __restrict__ shift,
                                                  float* __restrict__ bufA,
                                                  const int* __restrict__ fl) {
    int fw = fl[3];
    __shared__ float w[HDIM][HDIM];
    __shared__ float rows[4][HDIM];
    int t = threadIdx.x, lane = t & 63, sub = t >> 6;
    for (int i = t; i < HDIM * HDIM; i += 256) w[i / HDIM][i % HDIM] = ldf(W, i, fw);
    __syncthreads();
    float sc = scale[lane], sh = shift[lane];
    for (int base = blockIdx.x * 4; base < N_NODES; base += gridDim.x * 4) {
        int v = base + sub;
        float r = fmaxf(bufB[v * HDIM + lane] * sc + sh, 0.f);
        rows[sub][lane] = r;
        __syncthreads();
        float acc = 0.f;
#pragma unroll
        for (int k = 0; k < HDIM; k++) acc += rows[sub][k] * w[k][lane];
        bufA[v * HDIM + lane] = acc;
        __syncthreads();
    }
}

__global__ void __launch_bounds__(256) sgcn10_finish3(const float* __restrict__ bufB,
                                                      const void* b3, const int* __restrict__ batch,
                                                      float* __restrict__ poolsum,
                                                      const int* __restrict__ fl) {
    int wide = fl[1], f1d = fl[2];
    int idx = blockIdx.x * blockDim.x + threadIdx.x;
    int v = idx >> 6, lane = idx & 63;
    if (v < N_NODES) {
        float val = bufB[v * HDIM + lane] + ldf(b3, lane, f1d);
        unsigned g = (unsigned)ld_batch(batch, v, wide);
        if (g < N_GRAPH) atomicAdd(&poolsum[g * HDIM + lane], val);
    }
}

__global__ void __launch_bounds__(64) sgcn10_head(const float* __restrict__ poolsum,
                                                  const float* __restrict__ cnts,
                                                  const void* gfeat, const void* Wg, const void* bg,
                                                  const void* Wp1, const void* bp1,
                                                  const void* Wp2, const void* bp2,
                                                  float* __restrict__ stage,
                                                  const int* __restrict__ fl) {
    int f1d = fl[2], fw = fl[3];
    int g = blockIdx.x, t = threadIdx.x;
    __shared__ float comb[HDIM + HDIM / 2];
    __shared__ float hid[HDIM];
    float cnt = fmaxf(cnts[g], 1.0f);
    comb[t] = poolsum[g * HDIM + t] / cnt;
    if (t < HDIM / 2) {
        float a = ldf(bg, t, f1d);
#pragma unroll
        for (int k = 0; k < GFEAT; k++)
            a += ldf(gfeat, g * GFEAT + k, fw) * ldf(Wg, k * (HDIM / 2) + t, fw);
        comb[HDIM + t] = fmaxf(a, 0.f);
    }
    __syncthreads();
    float a = ldf(bp1, t, f1d);
    for (int k = 0; k < HDIM + HDIM / 2; k++) a += comb[k] * ldf(Wp1, k * HDIM + t, fw);
    hid[t] = fmaxf(a, 0.f);
    __syncthreads();
    if (t < T_OUT) {
        float o = ldf(bp2, t, f1d);
#pragma unroll
        for (int k = 0; k < HDIM; k++) o += hid[k] * ldf(Wp2, k * T_OUT + t, fw);
        stage[g * T_OUT + t] = o;
    }
}

// mux: fp32 result, or fp32 beacon 200+4*code if any validator red
__global__ void sgcn10_final(const float* __restrict__ stage, float* out,
                             const int* __restrict__ fl) {
    int i = blockIdx.x * blockDim.x + threadIdx.x;
    if (i >= N_GRAPH * T_OUT) return;
    int code = fl[0] * 1 + fl[1] * 2 + fl[4] * 4
             + (fl[8] ? 0 : 8) + (fl[9] ? 0 : 16) + (fl[10] ? 0 : 32);
    float V = 200.f + 4.f * (float)code;
    out[i] = (code == 0) ? stage[i] : V;
}

extern "C" __attribute__((visibility("default")))
void kernel_launch(void* const* d_in, const int* in_sizes, int n_in,
                   void* d_out, int out_size, void* d_ws, size_t ws_size,
                   hipStream_t stream) {
    static const int exp_sizes[20] = {700000, 10000, 448, 64, 4096, 64, 4096, 64,
                                      64, 64, 64, 64, 320, 32, 6144, 64, 320, 5,
                                      2400000, 100000};
    bool ok = (n_in == 20) && (out_size == N_GRAPH * T_OUT);
    if (ok) for (int i = 0; i < 20; i++) ok = ok && (in_sizes[i] == exp_sizes[i]);
    if (!ok) {
        sgcn10_fill<<<(out_size + 255) / 256, 256, 0, stream>>>((float*)d_out, out_size, 900.0f);
        return;
    }
    const size_t need = (size_t)(16 + N_NODES + N_GRAPH + 4 * HDIM + N_GRAPH * HDIM
                                 + 2 * (size_t)N_NODES * HDIM + N_GRAPH * T_OUT) * 4;
    if (ws_size < need) {
        sgcn10_fill<<<(out_size + 255) / 256, 256, 0, stream>>>((float*)d_out, out_size, 500.0f);
        return;
    }

    const void* x      = d_in[0];
    const void* gfeat  = d_in[1];
    const void* W1     = d_in[2];
    const void* b1     = d_in[3];
    const void* W2     = d_in[4];
    const void* b2     = d_in[5];
    const void* W3     = d_in[6];
    const void* b3     = d_in[7];
    const void* gamma1 = d_in[8];
    const void* beta1  = d_in[9];
    const void* gamma2 = d_in[10];
    const void* beta2  = d_in[11];
    const void* Wg     = d_in[12];
    const void* bg     = d_in[13];
    const void* Wp1    = d_in[14];
    const void* bp1    = d_in[15];
    const void* Wp2    = d_in[16];
    const void* bp2    = d_in[17];
    const int* edge  = (const int*)d_in[18];
    const int* batch = (const int*)d_in[19];

    int*   flags   = (int*)d_ws;                    // 16 ints
    float* dis     = (float*)d_ws + 16;             // N (deg -> dis)
    float* cnts    = dis + N_NODES;                 // G
    float* sums    = cnts + N_GRAPH;                // H
    float* sumsq   = sums + HDIM;                   // H
    float* scale   = sumsq + HDIM;                  // H
    float* shift   = scale + HDIM;                  // H
    float* poolsum = shift + HDIM;                  // G*H
    float* bufA    = poolsum + N_GRAPH * HDIM;      // N*H
    float* bufB    = bufA + (size_t)N_NODES * HDIM; // N*H
    float* stage   = bufB + (size_t)N_NODES * HDIM; // G*T

    sgcn10_probe<<<1, 256, 0, stream>>>(edge, batch, (const unsigned*)gamma1,
                                        (const unsigned short*)x, (const unsigned short*)W1,
                                        (const unsigned short*)W2, flags);

    int zcount = N_NODES + N_GRAPH + 4 * HDIM + N_GRAPH * HDIM;
    sgcn10_zero<<<(zcount + 255) / 256, 256, 0, stream>>>(dis, zcount);
    sgcn10_vsort<<<(N_NODES + 255) / 256, 256, 0, stream>>>(batch, flags, flags);

    sgcn10_deg<<<(N_EDGES + 255) / 256, 256, 0, stream>>>(edge, dis, flags);
    sgcn10_vdeg<<<1, 256, 0, stream>>>(dis, flags);
    sgcn10_dis_cnt<<<(N_NODES + 255) / 256, 256, 0, stream>>>(dis, batch, cnts, flags);
    sgcn10_vcnt<<<1, 256, 0, stream>>>(cnts, flags);

    const int NB_NH = (N_NODES * HDIM) / 256;
    // layer 1
    sgcn10_l1<<<4096, 256, 0, stream>>>(x, W1, bufA, flags);
    sgcn10_self<<<NB_NH, 256, 0, stream>>>(bufA, dis, bufB);
    sgcn10_scatter<<<N_EDGES / 4, 256, 0, stream>>>(edge, bufA, dis, bufB, flags);
    sgcn10_finish_bn<<<2048, 256, 0, stream>>>(bufB, b1, sums, sumsq, flags);
    sgcn10_bn_final<<<1, 64, 0, stream>>>(sums, sumsq, gamma1, beta1, scale, shift, flags);

    // layer 2
    sgcn10_l23<<<4096, 256, 0, stream>>>(bufB, W2, scale, shift, bufA, flags);
    sgcn10_self<<<NB_NH, 256, 0, stream>>>(bufA, dis, bufB);
    sgcn10_scatter<<<N_EDGES / 4, 256, 0, stream>>>(edge, bufA, dis, bufB, flags);
    sgcn10_finish_bn<<<2048, 256, 0, stream>>>(bufB, b2, sums, sumsq, flags);
    sgcn10_bn_final<<<1, 64, 0, stream>>>(sums, sumsq, gamma2, beta2, scale, shift, flags);

    // layer 3
    sgcn10_l23<<<4096, 256, 0, stream>>>(bufB, W3, scale, shift, bufA, flags);
    sgcn10_self<<<NB_NH, 256, 0, stream>>>(bufA, dis, bufB);
    sgcn10_scatter<<<N_EDGES / 4, 256, 0, stream>>>(edge, bufA, dis, bufB, flags);
    sgcn10_finish3<<<NB_NH, 256, 0, stream>>>(bufB, b3, batch, poolsum, flags);

    // head -> staging -> fp32 mux
    sgcn10_head<<<N_GRAPH, 64, 0, stream>>>(poolsum, cnts, gfeat, Wg, bg, Wp1, bp1, Wp2, bp2,
                                            stage, flags);
    sgcn10_final<<<(N_GRAPH * T_OUT + 255) / 256, 256, 0, stream>>>(
        stage, (float*)d_out, flags);
}

// Round 11
// 820.614 us; speedup vs baseline: 1.9096x; 1.9096x over previous
//
#include <hip/hip_runtime.h>
#include <hip/hip_bf16.h>

#define N_NODES 100000
#define N_EDGES 1200000
#define N_GRAPH 1000
#define F_INN   7
#define HDIM    64
#define GFEAT   10
#define T_OUT   5
#define EPSF    1e-5f
#define NBLK_SCAN ((N_NODES + 255) / 256)   // 391

// flags: [0]=edge wide(int64) [1]=batch wide [2]=1D fp32 [3]=world fp32

__device__ __forceinline__ float ldf(const void* p, int i, int isf32) {
    return isf32 ? ((const float*)p)[i]
                 : __bfloat162float(((const __hip_bfloat16*)p)[i]);
}
// edge layout: first half = src, second half = dst (verified round 10)
__device__ __forceinline__ int ld_src(const int* edge, int e, int wide) {
    return wide ? edge[2 * e] : edge[e];
}
__device__ __forceinline__ int ld_dst(const int* edge, int e, int wide) {
    return wide ? edge[2 * (N_EDGES + e)] : edge[N_EDGES + e];
}
__device__ __forceinline__ int ld_batch(const int* batch, int v, int wide) {
    return wide ? batch[2 * v] : batch[v];
}

__global__ void SimpleGCN_6640019440134_kernel() {}

__global__ void s11_fill(float* out, int n, float val) {
    int i = blockIdx.x * blockDim.x + threadIdx.x;
    if (i < n) out[i] = val;
}

__global__ void __launch_bounds__(256) s11_probe(const int* edge, const int* batch,
                                                 const unsigned* g1,
                                                 const unsigned short* x,
                                                 const unsigned short* W1,
                                                 const unsigned short* W2,
                                                 int* flags) {
    __shared__ int sh[8];
    int t = threadIdx.x;
    if (t < 8) sh[t] = 0;
    __syncthreads();
    { int pos = 1 + 2 * 4687 * t; if (edge[pos] != 0) atomicOr(&sh[0], 1); }
    { int pos = (N_NODES - 511) + 2 * t; if (batch[pos] != 0) atomicOr(&sh[1], 1); }
    if (t < 16 && g1[t] != 0x3F800000u) atomicOr(&sh[2], 1);
    {
        int e = (x[t] >> 7) & 0xFF;  if (e >= 100 && e <= 140) atomicAdd(&sh[3], 1);
        e = (W1[t] >> 7) & 0xFF;     if (e >= 100 && e <= 140) atomicAdd(&sh[4], 1);
        e = (W2[t] >> 7) & 0xFF;     if (e >= 100 && e <= 140) atomicAdd(&sh[5], 1);
    }
    __syncthreads();
    if (t == 0) {
        flags[0] = (sh[0] == 0);
        flags[1] = (sh[1] == 0);
        flags[2] = (sh[2] == 0);
        int fx = (sh[3] < 192), fw1 = (sh[4] < 192), fw2 = (sh[5] < 192);
        flags[3] = (fx + fw1 + fw2 >= 2);
    }
}

__global__ void s11_zero(int* zbuf, int zcount) {
    int i = blockIdx.x * blockDim.x + threadIdx.x;
    if (i < zcount) zbuf[i] = 0;
}

// in-degree histogram (int)
__global__ void s11_deg(const int* __restrict__ edge, int* degi, const int* __restrict__ fl) {
    int wide = fl[0];
    int e = blockIdx.x * blockDim.x + threadIdx.x;
    if (e < N_EDGES) {
        unsigned d = (unsigned)ld_dst(edge, e, wide);
        if (d < N_NODES) atomicAdd(&degi[d], 1);
    }
}

// two-level exclusive scan of degi -> cursor (=rowptr)
__global__ void __launch_bounds__(256) s11_scan1(const int* __restrict__ degi,
                                                 int* __restrict__ cursor, int* __restrict__ bsum) {
    __shared__ int tmp[256];
    int i = blockIdx.x * 256 + threadIdx.x;
    int v = (i < N_NODES) ? degi[i] : 0;
    tmp[threadIdx.x] = v;
    __syncthreads();
    for (int o = 1; o < 256; o <<= 1) {
        int t = (threadIdx.x >= o) ? tmp[threadIdx.x - o] : 0;
        __syncthreads();
        tmp[threadIdx.x] += t;
        __syncthreads();
    }
    if (i < N_NODES) cursor[i] = tmp[threadIdx.x] - v;     // local exclusive
    if (threadIdx.x == 255) bsum[blockIdx.x] = tmp[255];   // block total
}

__global__ void __launch_bounds__(512) s11_scan2(int* bsum) {
    __shared__ int tmp[512];
    int t = threadIdx.x;
    int v = (t < NBLK_SCAN) ? bsum[t] : 0;
    tmp[t] = v;
    __syncthreads();
    for (int o = 1; o < 512; o <<= 1) {
        int a = (t >= o) ? tmp[t - o] : 0;
        __syncthreads();
        tmp[t] += a;
        __syncthreads();
    }
    if (t < NBLK_SCAN) bsum[t] = tmp[t] - v;               // exclusive
}

__global__ void __launch_bounds__(256) s11_scan3(int* cursor, const int* __restrict__ bsum) {
    int i = blockIdx.x * 256 + threadIdx.x;
    if (i < N_NODES) cursor[i] += bsum[blockIdx.x];
}

// dis = rsqrt(deg+1); per-graph counts
__global__ void s11_dis_cnt(const int* __restrict__ degi, float* dis,
                            const int* __restrict__ batch, float* cnts,
                            const int* __restrict__ fl) {
    int wide = fl[1];
    int v = blockIdx.x * blockDim.x + threadIdx.x;
    if (v < N_NODES) {
        dis[v] = rsqrtf((float)degi[v] + 1.0f);
        unsigned g = (unsigned)ld_batch(batch, v, wide);
        if (g < N_GRAPH) atomicAdd(&cnts[g], 1.0f);
    }
}

// CSR fill: cursor[v] ends at rowptr[v]+deg[v] (row end); start = cursor[v-1]
__global__ void s11_csrfill(const int* __restrict__ edge, int* cursor,
                            int* __restrict__ csr_src, const int* __restrict__ fl) {
    int wide = fl[0];
    int e = blockIdx.x * blockDim.x + threadIdx.x;
    if (e < N_EDGES) {
        unsigned s = (unsigned)ld_src(edge, e, wide);
        unsigned d = (unsigned)ld_dst(edge, e, wide);
        if (s < N_NODES && d < N_NODES) {
            int slot = atomicAdd(&cursor[d], 1);
            csr_src[slot] = (int)s;
        }
    }
}

// LAYER 1 fused: agg_x = CSR-gather of x (7 ch), then @W1 + b1, BN stats.
// One wave per node (grid-strided); lanes 0..6 aggregate channels, all lanes matmul.
__global__ void __launch_bounds__(256) s11_gx_mm_bn(const void* x, const void* W1, const void* b1,
                                                    const float* __restrict__ dis,
                                                    const int* __restrict__ cursor,
                                                    const int* __restrict__ csr_src,
                                                    float* __restrict__ bufB,
                                                    float* sums, float* sumsq,
                                                    const int* __restrict__ fl) {
    int fw = fl[3], f1d = fl[2];
    __shared__ float w[F_INN][HDIM];
    __shared__ float shs[4][HDIM], shs2[4][HDIM];
    int t = threadIdx.x, lane = t & 63, sub = t >> 6;
    for (int i = t; i < F_INN * HDIM; i += 256) w[i / HDIM][i % HDIM] = ldf(W1, i, fw);
    __syncthreads();
    float bb = ldf(b1, lane, f1d);
    float s1 = 0.f, s2 = 0.f;
    for (int v = blockIdx.x * 4 + sub; v < N_NODES; v += gridDim.x * 4) {
        int end = cursor[v];
        int start = (v == 0) ? 0 : cursor[v - 1];
        float disv = dis[v];
        float aggc = 0.f;
        if (lane < F_INN) aggc = ldf(x, v * F_INN + lane, fw) * disv * disv;
        for (int j = start; j < end; j++) {
            int s = csr_src[j];
            float wj = dis[s] * disv;
            if (lane < F_INN) aggc += ldf(x, s * F_INN + lane, fw) * wj;
        }
        // matmul: val[h] = sum_c aggc(c) * W1[c][h] + b1
        float acc = bb;
#pragma unroll
        for (int c = 0; c < F_INN; c++) {
            float ac = __shfl(aggc, c);
            acc += ac * w[c][lane];
        }
        bufB[v * HDIM + lane] = acc;
        s1 += acc; s2 += acc * acc;
    }
    shs[sub][lane] = s1; shs2[sub][lane] = s2;
    __syncthreads();
    if (sub == 0) {
        float ts  = shs[0][lane] + shs[1][lane] + shs[2][lane] + shs[3][lane];
        float ts2 = shs2[0][lane] + shs2[1][lane] + shs2[2][lane] + shs2[3][lane];
        atomicAdd(&sums[lane], ts);
        atomicAdd(&sumsq[lane], ts2);
    }
}

__global__ void s11_bn_final(float* sums, float* sumsq, const void* gamma, const void* beta,
                             float* scale, float* shift, const int* __restrict__ fl) {
    int f1d = fl[2];
    int j = threadIdx.x;
    float mean = sums[j] / (float)N_NODES;
    float var  = sumsq[j] / (float)N_NODES - mean * mean;
    float sc = ldf(gamma, j, f1d) * rsqrtf(var + EPSF);
    scale[j] = sc;
    shift[j] = ldf(beta, j, f1d) - mean * sc;
    sums[j] = 0.f; sumsq[j] = 0.f;
}

// bufA[v] = relu(bufB[v]*sc+sh) @ W
__global__ void __launch_bounds__(256) s11_mm(const float* __restrict__ bufB, const void* W,
                                              const float* __restrict__ scale,
                                              const float* __restrict__ shift,
                                              float* __restrict__ bufA,
                                              const int* __restrict__ fl) {
    int fw = fl[3];
    __shared__ float w[HDIM][HDIM];
    __shared__ float rows[4][HDIM];
    int t = threadIdx.x, lane = t & 63, sub = t >> 6;
    for (int i = t; i < HDIM * HDIM; i += 256) w[i / HDIM][i % HDIM] = ldf(W, i, fw);
    __syncthreads();
    float sc = scale[lane], sh = shift[lane];
    for (int base = blockIdx.x * 4; base < N_NODES; base += gridDim.x * 4) {
        int v = base + sub;
        float r = fmaxf(bufB[v * HDIM + lane] * sc + sh, 0.f);
        rows[sub][lane] = r;
        __syncthreads();
        float acc = 0.f;
#pragma unroll
        for (int k = 0; k < HDIM; k++) acc += rows[sub][k] * w[k][lane];
        bufA[v * HDIM + lane] = acc;
        __syncthreads();
    }
}

// gather-aggregate 64ch + bias, write bufB, BN stats (no atomics on bufB)
__global__ void __launch_bounds__(256) s11_gather_bn(const float* __restrict__ bufA,
                                                     const float* __restrict__ dis,
                                                     const int* __restrict__ cursor,
                                                     const int* __restrict__ csr_src,
                                                     const void* b,
                                                     float* __restrict__ bufB,
                                                     float* sums, float* sumsq,
                                                     const int* __restrict__ fl) {
    int f1d = fl[2];
    __shared__ float shs[4][HDIM], shs2[4][HDIM];
    int t = threadIdx.x, lane = t & 63, sub = t >> 6;
    float bb = ldf(b, lane, f1d);
    float s1 = 0.f, s2 = 0.f;
    for (int v = blockIdx.x * 4 + sub; v < N_NODES; v += gridDim.x * 4) {
        int end = cursor[v];
        int start = (v == 0) ? 0 : cursor[v - 1];
        float disv = dis[v];
        float acc = bufA[v * HDIM + lane] * disv * disv;
        for (int j = start; j < end; j++) {
            int s = csr_src[j];
            float wj = dis[s] * disv;
            acc += bufA[s * HDIM + lane] * wj;
        }
        float val = acc + bb;
        bufB[v * HDIM + lane] = val;
        s1 += val; s2 += val * val;
    }
    shs[sub][lane] = s1; shs2[sub][lane] = s2;
    __syncthreads();
    if (sub == 0) {
        float ts  = shs[0][lane] + shs[1][lane] + shs[2][lane] + shs[3][lane];
        float ts2 = shs2[0][lane] + shs2[1][lane] + shs2[2][lane] + shs2[3][lane];
        atomicAdd(&sums[lane], ts);
        atomicAdd(&sumsq[lane], ts2);
    }
}

// layer-3 gather + bias + pool
__global__ void __launch_bounds__(256) s11_gather_pool(const float* __restrict__ bufA,
                                                       const float* __restrict__ dis,
                                                       const int* __restrict__ cursor,
                                                       const int* __restrict__ csr_src,
                                                       const void* b3,
                                                       const int* __restrict__ batch,
                                                       float* __restrict__ poolsum,
                                                       const int* __restrict__ fl) {
    int f1d = fl[2], wide = fl[1];
    int t = threadIdx.x, lane = t & 63, sub = t >> 6;
    float bb = ldf(b3, lane, f1d);
    for (int v = blockIdx.x * 4 + sub; v < N_NODES; v += gridDim.x * 4) {
        int end = cursor[v];
        int start = (v == 0) ? 0 : cursor[v - 1];
        float disv = dis[v];
        float acc = bufA[v * HDIM + lane] * disv * disv;
        for (int j = start; j < end; j++) {
            int s = csr_src[j];
            float wj = dis[s] * disv;
            acc += bufA[s * HDIM + lane] * wj;
        }
        unsigned g = (unsigned)ld_batch(batch, v, wide);
        if (g < N_GRAPH) atomicAdd(&poolsum[g * HDIM + lane], acc + bb);
    }
}

__global__ void __launch_bounds__(64) s11_head(const float* __restrict__ poolsum,
                                               const float* __restrict__ cnts,
                                               const void* gfeat, const void* Wg, const void* bg,
                                               const void* Wp1, const void* bp1,
                                               const void* Wp2, const void* bp2,
                                               float* __restrict__ out,
                                               const int* __restrict__ fl) {
    int f1d = fl[2], fw = fl[3];
    int g = blockIdx.x, t = threadIdx.x;
    __shared__ float comb[HDIM + HDIM / 2];
    __shared__ float hid[HDIM];
    float cnt = fmaxf(cnts[g], 1.0f);
    comb[t] = poolsum[g * HDIM + t] / cnt;
    if (t < HDIM / 2) {
        float a = ldf(bg, t, f1d);
#pragma unroll
        for (int k = 0; k < GFEAT; k++)
            a += ldf(gfeat, g * GFEAT + k, fw) * ldf(Wg, k * (HDIM / 2) + t, fw);
        comb[HDIM + t] = fmaxf(a, 0.f);
    }
    __syncthreads();
    float a = ldf(bp1, t, f1d);
    for (int k = 0; k < HDIM + HDIM / 2; k++) a += comb[k] * ldf(Wp1, k * HDIM + t, fw);
    hid[t] = fmaxf(a, 0.f);
    __syncthreads();
    if (t < T_OUT) {
        float o = ldf(bp2, t, f1d);
#pragma unroll
        for (int k = 0; k < HDIM; k++) o += hid[k] * ldf(Wp2, k * T_OUT + t, fw);
        out[g * T_OUT + t] = o;
    }
}

extern "C" __attribute__((visibility("default")))
void kernel_launch(void* const* d_in, const int* in_sizes, int n_in,
                   void* d_out, int out_size, void* d_ws, size_t ws_size,
                   hipStream_t stream) {
    static const int exp_sizes[20] = {700000, 10000, 448, 64, 4096, 64, 4096, 64,
                                      64, 64, 64, 64, 320, 32, 6144, 64, 320, 5,
                                      2400000, 100000};
    bool ok = (n_in == 20) && (out_size == N_GRAPH * T_OUT);
    if (ok) for (int i = 0; i < 20; i++) ok = ok && (in_sizes[i] == exp_sizes[i]);
    if (!ok) {
        s11_fill<<<(out_size + 255) / 256, 256, 0, stream>>>((float*)d_out, out_size, 900.0f);
        return;
    }

    const void* x      = d_in[0];
    const void* gfeat  = d_in[1];
    const void* W1     = d_in[2];
    const void* b1     = d_in[3];
    const void* W2     = d_in[4];
    const void* b2     = d_in[5];
    const void* W3     = d_in[6];
    const void* b3     = d_in[7];
    const void* gamma1 = d_in[8];
    const void* beta1  = d_in[9];
    const void* gamma2 = d_in[10];
    const void* beta2  = d_in[11];
    const void* Wg     = d_in[12];
    const void* bg     = d_in[13];
    const void* Wp1    = d_in[14];
    const void* bp1    = d_in[15];
    const void* Wp2    = d_in[16];
    const void* bp2    = d_in[17];
    const int* edge  = (const int*)d_in[18];
    const int* batch = (const int*)d_in[19];

    // workspace layout (4-byte words)
    int*   flags   = (int*)d_ws;                      // 16
    int*   degi    = flags + 16;                      // N
    float* dis     = (float*)(degi + N_NODES);        // N
    float* cnts    = dis + N_NODES;                   // G
    float* sums    = cnts + N_GRAPH;                  // H
    float* sumsq   = sums + HDIM;                     // H
    float* scale   = sumsq + HDIM;                    // H
    float* shift   = scale + HDIM;                    // H
    float* poolsum = shift + HDIM;                    // G*H
    int*   cursor  = (int*)(poolsum + N_GRAPH * HDIM);// N
    int*   bsum    = cursor + N_NODES;                // 512
    int*   csr_src = bsum + 512;                      // E
    float* bufA    = (float*)(csr_src + N_EDGES);     // N*H
    float* bufB    = bufA + (size_t)N_NODES * HDIM;   // N*H

    const size_t need = (size_t)(16 + 2 * N_NODES + N_GRAPH + 4 * HDIM + N_GRAPH * HDIM
                                 + N_NODES + 512 + N_EDGES
                                 + 2 * (size_t)N_NODES * HDIM) * 4;
    if (ws_size < need) {
        s11_fill<<<(out_size + 255) / 256, 256, 0, stream>>>((float*)d_out, out_size, 500.0f);
        return;
    }

    s11_probe<<<1, 256, 0, stream>>>(edge, batch, (const unsigned*)gamma1,
                                     (const unsigned short*)x, (const unsigned short*)W1,
                                     (const unsigned short*)W2, flags);

    // zero degi, cnts, sums, sumsq, poolsum (contiguous span degi..shift covers extras harmlessly)
    int zcount = N_NODES + (N_NODES) + N_GRAPH + 4 * HDIM + N_GRAPH * HDIM; // degi..poolsum end
    s11_zero<<<(zcount + 255) / 256, 256, 0, stream>>>(degi, zcount);

    s11_deg<<<(N_EDGES + 255) / 256, 256, 0, stream>>>(edge, degi, flags);
    s11_scan1<<<NBLK_SCAN, 256, 0, stream>>>(degi, cursor, bsum);
    s11_scan2<<<1, 512, 0, stream>>>(bsum);
    s11_scan3<<<NBLK_SCAN, 256, 0, stream>>>(cursor, bsum);
    s11_dis_cnt<<<(N_NODES + 255) / 256, 256, 0, stream>>>(degi, dis, batch, cnts, flags);
    s11_csrfill<<<(N_EDGES + 255) / 256, 256, 0, stream>>>(edge, cursor, csr_src, flags);

    // layer 1 (fused gather-x + matmul + BN stats)
    s11_gx_mm_bn<<<2048, 256, 0, stream>>>(x, W1, b1, dis, cursor, csr_src,
                                           bufB, sums, sumsq, flags);
    s11_bn_final<<<1, 64, 0, stream>>>(sums, sumsq, gamma1, beta1, scale, shift, flags);

    // layer 2
    s11_mm<<<4096, 256, 0, stream>>>(bufB, W2, scale, shift, bufA, flags);
    s11_gather_bn<<<2048, 256, 0, stream>>>(bufA, dis, cursor, csr_src, b2,
                                            bufB, sums, sumsq, flags);
    s11_bn_final<<<1, 64, 0, stream>>>(sums, sumsq, gamma2, beta2, scale, shift, flags);

    // layer 3
    s11_mm<<<4096, 256, 0, stream>>>(bufB, W3, scale, shift, bufA, flags);
    s11_gather_pool<<<2048, 256, 0, stream>>>(bufA, dis, cursor, csr_src, b3,
                                              batch, poolsum, flags);

    // head
    s11_head<<<N_GRAPH, 64, 0, stream>>>(poolsum, cnts, gfeat, Wg, bg, Wp1, bp1, Wp2, bp2,
                                         (float*)d_out, flags);
}

// Round 12
// 747.195 us; speedup vs baseline: 2.0972x; 1.0983x over previous
//
#include <hip/hip_runtime.h>
#include <hip/hip_bf16.h>

#define N_NODES 100000
#define N_EDGES 1200000
#define N_GRAPH 1000
#define F_INN   7
#define HDIM    64
#define GFEAT   10
#define T_OUT   5
#define EPSF    1e-5f
#define NBLK_SCAN ((N_NODES + 255) / 256)   // 391

// flags: [0]=edge wide(int64) [1]=batch wide [2]=1D fp32 [3]=world fp32

__device__ __forceinline__ float ldf(const void* p, int i, int isf32) {
    return isf32 ? ((const float*)p)[i]
                 : __bfloat162float(((const __hip_bfloat16*)p)[i]);
}
__device__ __forceinline__ float b2f(__hip_bfloat16 v) { return __bfloat162float(v); }
// edge layout: first half = src, second half = dst (verified round 10)
__device__ __forceinline__ int ld_src(const int* edge, int e, int wide) {
    return wide ? edge[2 * e] : edge[e];
}
__device__ __forceinline__ int ld_dst(const int* edge, int e, int wide) {
    return wide ? edge[2 * (N_EDGES + e)] : edge[N_EDGES + e];
}
__device__ __forceinline__ int ld_batch(const int* batch, int v, int wide) {
    return wide ? batch[2 * v] : batch[v];
}

__global__ void SimpleGCN_6640019440134_kernel() {}

__global__ void s12_fill(float* out, int n, float val) {
    int i = blockIdx.x * blockDim.x + threadIdx.x;
    if (i < n) out[i] = val;
}

__global__ void __launch_bounds__(256) s12_probe(const int* edge, const int* batch,
                                                 const unsigned* g1,
                                                 const unsigned short* x,
                                                 const unsigned short* W1,
                                                 const unsigned short* W2,
                                                 int* flags) {
    __shared__ int sh[8];
    int t = threadIdx.x;
    if (t < 8) sh[t] = 0;
    __syncthreads();
    { int pos = 1 + 2 * 4687 * t; if (edge[pos] != 0) atomicOr(&sh[0], 1); }
    { int pos = (N_NODES - 511) + 2 * t; if (batch[pos] != 0) atomicOr(&sh[1], 1); }
    if (t < 16 && g1[t] != 0x3F800000u) atomicOr(&sh[2], 1);
    {
        int e = (x[t] >> 7) & 0xFF;  if (e >= 100 && e <= 140) atomicAdd(&sh[3], 1);
        e = (W1[t] >> 7) & 0xFF;     if (e >= 100 && e <= 140) atomicAdd(&sh[4], 1);
        e = (W2[t] >> 7) & 0xFF;     if (e >= 100 && e <= 140) atomicAdd(&sh[5], 1);
    }
    __syncthreads();
    if (t == 0) {
        flags[0] = (sh[0] == 0);
        flags[1] = (sh[1] == 0);
        flags[2] = (sh[2] == 0);
        int fx = (sh[3] < 192), fw1 = (sh[4] < 192), fw2 = (sh[5] < 192);
        flags[3] = (fx + fw1 + fw2 >= 2);
    }
}

__global__ void s12_zero(int* zbuf, int zcount) {
    int i = blockIdx.x * blockDim.x + threadIdx.x;
    if (i < zcount) zbuf[i] = 0;
}

__global__ void s12_deg(const int* __restrict__ edge, int* degi, const int* __restrict__ fl) {
    int wide = fl[0];
    int e = blockIdx.x * blockDim.x + threadIdx.x;
    if (e < N_EDGES) {
        unsigned d = (unsigned)ld_dst(edge, e, wide);
        if (d < N_NODES) atomicAdd(&degi[d], 1);
    }
}

__global__ void __launch_bounds__(256) s12_scan1(const int* __restrict__ degi,
                                                 int* __restrict__ cursor, int* __restrict__ bsum) {
    __shared__ int tmp[256];
    int i = blockIdx.x * 256 + threadIdx.x;
    int v = (i < N_NODES) ? degi[i] : 0;
    tmp[threadIdx.x] = v;
    __syncthreads();
    for (int o = 1; o < 256; o <<= 1) {
        int t = (threadIdx.x >= o) ? tmp[threadIdx.x - o] : 0;
        __syncthreads();
        tmp[threadIdx.x] += t;
        __syncthreads();
    }
    if (i < N_NODES) cursor[i] = tmp[threadIdx.x] - v;
    if (threadIdx.x == 255) bsum[blockIdx.x] = tmp[255];
}

__global__ void __launch_bounds__(512) s12_scan2(int* bsum) {
    __shared__ int tmp[512];
    int t = threadIdx.x;
    int v = (t < NBLK_SCAN) ? bsum[t] : 0;
    tmp[t] = v;
    __syncthreads();
    for (int o = 1; o < 512; o <<= 1) {
        int a = (t >= o) ? tmp[t - o] : 0;
        __syncthreads();
        tmp[t] += a;
        __syncthreads();
    }
    if (t < NBLK_SCAN) bsum[t] = tmp[t] - v;
}

__global__ void __launch_bounds__(256) s12_scan3(int* cursor, const int* __restrict__ bsum) {
    int i = blockIdx.x * 256 + threadIdx.x;
    if (i < N_NODES) cursor[i] += bsum[blockIdx.x];
}

__global__ void s12_dis_cnt(const int* __restrict__ degi, float* dis,
                            const int* __restrict__ batch, float* cnts,
                            const int* __restrict__ fl) {
    int wide = fl[1];
    int v = blockIdx.x * blockDim.x + threadIdx.x;
    if (v < N_NODES) {
        dis[v] = rsqrtf((float)degi[v] + 1.0f);
        unsigned g = (unsigned)ld_batch(batch, v, wide);
        if (g < N_GRAPH) atomicAdd(&cnts[g], 1.0f);
    }
}

__global__ void s12_csrfill(const int* __restrict__ edge, int* cursor,
                            int* __restrict__ csr_src, const int* __restrict__ fl) {
    int wide = fl[0];
    int e = blockIdx.x * blockDim.x + threadIdx.x;
    if (e < N_EDGES) {
        unsigned s = (unsigned)ld_src(edge, e, wide);
        unsigned d = (unsigned)ld_dst(edge, e, wide);
        if (s < N_NODES && d < N_NODES) {
            int slot = atomicAdd(&cursor[d], 1);
            csr_src[slot] = (int)s;
        }
    }
}

// x̃[v*8+c] = bf16(x[v,c]*dis[v]), 8-padded rows (16B aligned)
__global__ void s12_xprep(const void* x, const float* __restrict__ dis,
                          __hip_bfloat16* __restrict__ xt, const int* __restrict__ fl) {
    int fw = fl[3];
    int i = blockIdx.x * blockDim.x + threadIdx.x;
    if (i < N_NODES * 8) {
        int v = i >> 3, c = i & 7;
        float val = (c < F_INN) ? ldf(x, v * F_INN + c, fw) * dis[v] : 0.f;
        xt[i] = __float2bfloat16(val);
    }
}

// layer 1: agg x̃ (8ch bf16, dis-folded), *dis[v], @W1 + b1, BN stats
__global__ void __launch_bounds__(256) s12_g7_mm_bn(const __hip_bfloat16* __restrict__ xt,
                                                    const void* W1, const void* b1,
                                                    const float* __restrict__ dis,
                                                    const int* __restrict__ cursor,
                                                    const int* __restrict__ csr,
                                                    float* __restrict__ bufB,
                                                    float* sums, float* sumsq,
                                                    const int* __restrict__ fl) {
    int fw = fl[3], f1d = fl[2];
    __shared__ float w[F_INN][HDIM];
    __shared__ float shs[4][HDIM], shs2[4][HDIM];
    int t = threadIdx.x, lane = t & 63, sub = t >> 6;
    for (int i = t; i < F_INN * HDIM; i += 256) w[i / HDIM][i % HDIM] = ldf(W1, i, fw);
    __syncthreads();
    float bb = ldf(b1, lane, f1d);
    float s1 = 0.f, s2 = 0.f;
    for (int v = blockIdx.x * 4 + sub; v < N_NODES; v += gridDim.x * 4) {
        int end = cursor[v];
        int start = (v == 0) ? 0 : cursor[v - 1];
        float aggc = (lane < 8) ? b2f(xt[v * 8 + lane]) : 0.f;
        int j = start;
        for (; j + 3 < end; j += 4) {
            int e0 = csr[j], e1 = csr[j + 1], e2 = csr[j + 2], e3 = csr[j + 3];
            if (lane < 8) {
                float a0 = b2f(xt[e0 * 8 + lane]);
                float a1 = b2f(xt[e1 * 8 + lane]);
                float a2 = b2f(xt[e2 * 8 + lane]);
                float a3 = b2f(xt[e3 * 8 + lane]);
                aggc += (a0 + a1) + (a2 + a3);
            }
        }
        for (; j < end; j++) {
            int s = csr[j];
            if (lane < 8) aggc += b2f(xt[s * 8 + lane]);
        }
        aggc *= dis[v];
        float acc = bb;
#pragma unroll
        for (int c = 0; c < F_INN; c++) acc += __shfl(aggc, c) * w[c][lane];
        bufB[v * HDIM + lane] = acc;
        s1 += acc; s2 += acc * acc;
    }
    shs[sub][lane] = s1; shs2[sub][lane] = s2;
    __syncthreads();
    if (sub == 0) {
        float ts  = shs[0][lane] + shs[1][lane] + shs[2][lane] + shs[3][lane];
        float ts2 = shs2[0][lane] + shs2[1][lane] + shs2[2][lane] + shs2[3][lane];
        atomicAdd(&sums[lane], ts);
        atomicAdd(&sumsq[lane], ts2);
    }
}

__global__ void s12_bn_final(float* sums, float* sumsq, const void* gamma, const void* beta,
                             float* scale, float* shift, const int* __restrict__ fl) {
    int f1d = fl[2];
    int j = threadIdx.x;
    float mean = sums[j] / (float)N_NODES;
    float var  = sumsq[j] / (float)N_NODES - mean * mean;
    float sc = ldf(gamma, j, f1d) * rsqrtf(var + EPSF);
    scale[j] = sc;
    shift[j] = ldf(beta, j, f1d) - mean * sc;
    sums[j] = 0.f; sumsq[j] = 0.f;
}

// r̃[v,c] = bf16(relu(bufB*sc+sh) * dis[v])
__global__ void s12_prep(const float* __restrict__ bufB,
                         const float* __restrict__ scale, const float* __restrict__ shift,
                         const float* __restrict__ dis, __hip_bfloat16* __restrict__ rt) {
    int i = blockIdx.x * blockDim.x + threadIdx.x;
    if (i < N_NODES * HDIM) {
        int v = i >> 6, c = i & 63;
        float r = fmaxf(bufB[i] * scale[c] + shift[c], 0.f) * dis[v];
        rt[i] = __float2bfloat16(r);
    }
}

// layers 2: agg r̃ (64ch bf16, dis-folded), *dis[v], @W + b, write bufB, BN stats
__global__ void __launch_bounds__(256) s12_gmm_bn(const __hip_bfloat16* __restrict__ rt,
                                                  const void* W, const void* b,
                                                  const float* __restrict__ dis,
                                                  const int* __restrict__ cursor,
                                                  const int* __restrict__ csr,
                                                  float* __restrict__ bufB,
                                                  float* sums, float* sumsq,
                                                  const int* __restrict__ fl) {
    int fw = fl[3], f1d = fl[2];
    __shared__ float w[HDIM][HDIM];
    __shared__ float rows[4][HDIM];
    __shared__ float shs[4][HDIM], shs2[4][HDIM];
    int t = threadIdx.x, lane = t & 63, sub = t >> 6;
    for (int i = t; i < HDIM * HDIM; i += 256) w[i / HDIM][i % HDIM] = ldf(W, i, fw);
    __syncthreads();
    float bb = ldf(b, lane, f1d);
    float s1 = 0.f, s2 = 0.f;
    for (int v = blockIdx.x * 4 + sub; v < N_NODES; v += gridDim.x * 4) {
        int end = cursor[v];
        int start = (v == 0) ? 0 : cursor[v - 1];
        float acc = b2f(rt[v * HDIM + lane]);
        int j = start;
        for (; j + 3 < end; j += 4) {
            int e0 = csr[j], e1 = csr[j + 1], e2 = csr[j + 2], e3 = csr[j + 3];
            float a0 = b2f(rt[e0 * HDIM + lane]);
            float a1 = b2f(rt[e1 * HDIM + lane]);
            float a2 = b2f(rt[e2 * HDIM + lane]);
            float a3 = b2f(rt[e3 * HDIM + lane]);
            acc += (a0 + a1) + (a2 + a3);
        }
        for (; j < end; j++) acc += b2f(rt[csr[j] * HDIM + lane]);
        acc *= dis[v];
        rows[sub][lane] = acc;
        __syncthreads();
        float val = bb;
#pragma unroll
        for (int k = 0; k < HDIM; k++) val += rows[sub][k] * w[k][lane];
        __syncthreads();
        bufB[v * HDIM + lane] = val;
        s1 += val; s2 += val * val;
    }
    shs[sub][lane] = s1; shs2[sub][lane] = s2;
    __syncthreads();
    if (sub == 0) {
        float ts  = shs[0][lane] + shs[1][lane] + shs[2][lane] + shs[3][lane];
        float ts2 = shs2[0][lane] + shs2[1][lane] + shs2[2][lane] + shs2[3][lane];
        atomicAdd(&sums[lane], ts);
        atomicAdd(&sumsq[lane], ts2);
    }
}

// layer 3: agg r̃, *dis[v], @W3 + b3, pool into poolsum
__global__ void __launch_bounds__(256) s12_gmm_pool(const __hip_bfloat16* __restrict__ rt,
                                                    const void* W3, const void* b3,
                                                    const float* __restrict__ dis,
                                                    const int* __restrict__ cursor,
                                                    const int* __restrict__ csr,
                                                    const int* __restrict__ batch,
                                                    float* __restrict__ poolsum,
                                                    const int* __restrict__ fl) {
    int fw = fl[3], f1d = fl[2], wide = fl[1];
    __shared__ float w[HDIM][HDIM];
    __shared__ float rows[4][HDIM];
    int t = threadIdx.x, lane = t & 63, sub = t >> 6;
    for (int i = t; i < HDIM * HDIM; i += 256) w[i / HDIM][i % HDIM] = ldf(W3, i, fw);
    __syncthreads();
    float bb = ldf(b3, lane, f1d);
    for (int v = blockIdx.x * 4 + sub; v < N_NODES; v += gridDim.x * 4) {
        int end = cursor[v];
        int start = (v == 0) ? 0 : cursor[v - 1];
        float acc = b2f(rt[v * HDIM + lane]);
        int j = start;
        for (; j + 3 < end; j += 4) {
            int e0 = csr[j], e1 = csr[j + 1], e2 = csr[j + 2], e3 = csr[j + 3];
            float a0 = b2f(rt[e0 * HDIM + lane]);
            float a1 = b2f(rt[e1 * HDIM + lane]);
            float a2 = b2f(rt[e2 * HDIM + lane]);
            float a3 = b2f(rt[e3 * HDIM + lane]);
            acc += (a0 + a1) + (a2 + a3);
        }
        for (; j < end; j++) acc += b2f(rt[csr[j] * HDIM + lane]);
        acc *= dis[v];
        rows[sub][lane] = acc;
        __syncthreads();
        float val = bb;
#pragma unroll
        for (int k = 0; k < HDIM; k++) val += rows[sub][k] * w[k][lane];
        __syncthreads();
        unsigned g = (unsigned)ld_batch(batch, v, wide);
        if (g < N_GRAPH) atomicAdd(&poolsum[g * HDIM + lane], val);
    }
}

__global__ void __launch_bounds__(64) s12_head(const float* __restrict__ poolsum,
                                               const float* __restrict__ cnts,
                                               const void* gfeat, const void* Wg, const void* bg,
                                               const void* Wp1, const void* bp1,
                                               const void* Wp2, const void* bp2,
                                               float* __restrict__ out,
                                               const int* __restrict__ fl) {
    int f1d = fl[2], fw = fl[3];
    int g = blockIdx.x, t = threadIdx.x;
    __shared__ float comb[HDIM + HDIM / 2];
    __shared__ float hid[HDIM];
    float cnt = fmaxf(cnts[g], 1.0f);
    comb[t] = poolsum[g * HDIM + t] / cnt;
    if (t < HDIM / 2) {
        float a = ldf(bg, t, f1d);
#pragma unroll
        for (int k = 0; k < GFEAT; k++)
            a += ldf(gfeat, g * GFEAT + k, fw) * ldf(Wg, k * (HDIM / 2) + t, fw);
        comb[HDIM + t] = fmaxf(a, 0.f);
    }
    __syncthreads();
    float a = ldf(bp1, t, f1d);
    for (int k = 0; k < HDIM + HDIM / 2; k++) a += comb[k] * ldf(Wp1, k * HDIM + t, fw);
    hid[t] = fmaxf(a, 0.f);
    __syncthreads();
    if (t < T_OUT) {
        float o = ldf(bp2, t, f1d);
#pragma unroll
        for (int k = 0; k < HDIM; k++) o += hid[k] * ldf(Wp2, k * T_OUT + t, fw);
        out[g * T_OUT + t] = o;
    }
}

extern "C" __attribute__((visibility("default")))
void kernel_launch(void* const* d_in, const int* in_sizes, int n_in,
                   void* d_out, int out_size, void* d_ws, size_t ws_size,
                   hipStream_t stream) {
    static const int exp_sizes[20] = {700000, 10000, 448, 64, 4096, 64, 4096, 64,
                                      64, 64, 64, 64, 320, 32, 6144, 64, 320, 5,
                                      2400000, 100000};
    bool ok = (n_in == 20) && (out_size == N_GRAPH * T_OUT);
    if (ok) for (int i = 0; i < 20; i++) ok = ok && (in_sizes[i] == exp_sizes[i]);
    if (!ok) {
        s12_fill<<<(out_size + 255) / 256, 256, 0, stream>>>((float*)d_out, out_size, 900.0f);
        return;
    }

    const void* x      = d_in[0];
    const void* gfeat  = d_in[1];
    const void* W1     = d_in[2];
    const void* b1     = d_in[3];
    const void* W2     = d_in[4];
    const void* b2     = d_in[5];
    const void* W3     = d_in[6];
    const void* b3     = d_in[7];
    const void* gamma1 = d_in[8];
    const void* beta1  = d_in[9];
    const void* gamma2 = d_in[10];
    const void* beta2  = d_in[11];
    const void* Wg     = d_in[12];
    const void* bg     = d_in[13];
    const void* Wp1    = d_in[14];
    const void* bp1    = d_in[15];
    const void* Wp2    = d_in[16];
    const void* bp2    = d_in[17];
    const int* edge  = (const int*)d_in[18];
    const int* batch = (const int*)d_in[19];

    // workspace layout (4-byte words)
    int*   flags   = (int*)d_ws;                        // 16
    int*   degi    = flags + 16;                        // N
    float* dis     = (float*)(degi + N_NODES);          // N
    float* cnts    = dis + N_NODES;                     // G
    float* sums    = cnts + N_GRAPH;                    // H
    float* sumsq   = sums + HDIM;                       // H
    float* scale   = sumsq + HDIM;                      // H
    float* shift   = scale + HDIM;                      // H
    float* poolsum = shift + HDIM;                      // G*H
    int*   cursor  = (int*)(poolsum + N_GRAPH * HDIM);  // N
    int*   bsum    = cursor + N_NODES;                  // 512
    int*   csr_src = bsum + 512;                        // E
    __hip_bfloat16* xt = (__hip_bfloat16*)(csr_src + N_EDGES);  // N*8 bf16 (N*4 words)
    __hip_bfloat16* rt = xt + (size_t)N_NODES * 8;              // N*64 bf16 (N*32 words)
    float* bufB    = (float*)(rt + (size_t)N_NODES * HDIM);     // N*H fp32

    const size_t need = (size_t)(16 + 3 * N_NODES + N_GRAPH + 4 * HDIM + N_GRAPH * HDIM
                                 + 512 + N_EDGES + 4 * N_NODES + 32 * N_NODES
                                 + 64 * (size_t)N_NODES) * 4;
    if (ws_size < need) {
        s12_fill<<<(out_size + 255) / 256, 256, 0, stream>>>((float*)d_out, out_size, 500.0f);
        return;
    }

    s12_probe<<<1, 256, 0, stream>>>(edge, batch, (const unsigned*)gamma1,
                                     (const unsigned short*)x, (const unsigned short*)W1,
                                     (const unsigned short*)W2, flags);

    // zero degi..poolsum span (covers degi, dis(harmless), cnts, sums, sumsq, scale, shift, poolsum)
    int zcount = 2 * N_NODES + N_GRAPH + 4 * HDIM + N_GRAPH * HDIM;
    s12_zero<<<(zcount + 255) / 256, 256, 0, stream>>>(degi, zcount);

    s12_deg<<<(N_EDGES + 255) / 256, 256, 0, stream>>>(edge, degi, flags);
    s12_scan1<<<NBLK_SCAN, 256, 0, stream>>>(degi, cursor, bsum);
    s12_scan2<<<1, 512, 0, stream>>>(bsum);
    s12_scan3<<<NBLK_SCAN, 256, 0, stream>>>(cursor, bsum);
    s12_dis_cnt<<<(N_NODES + 255) / 256, 256, 0, stream>>>(degi, dis, batch, cnts, flags);
    s12_csrfill<<<(N_EDGES + 255) / 256, 256, 0, stream>>>(edge, cursor, csr_src, flags);

    // layer 1
    s12_xprep<<<(N_NODES * 8 + 255) / 256, 256, 0, stream>>>(x, dis, xt, flags);
    s12_g7_mm_bn<<<2048, 256, 0, stream>>>(xt, W1, b1, dis, cursor, csr_src,
                                           bufB, sums, sumsq, flags);
    s12_bn_final<<<1, 64, 0, stream>>>(sums, sumsq, gamma1, beta1, scale, shift, flags);

    // layer 2
    s12_prep<<<(N_NODES * HDIM + 255) / 256, 256, 0, stream>>>(bufB, scale, shift, dis, rt);
    s12_gmm_bn<<<2048, 256, 0, stream>>>(rt, W2, b2, dis, cursor, csr_src,
                                         bufB, sums, sumsq, flags);
    s12_bn_final<<<1, 64, 0, stream>>>(sums, sumsq, gamma2, beta2, scale, shift, flags);

    // layer 3
    s12_prep<<<(N_NODES * HDIM + 255) / 256, 256, 0, stream>>>(bufB, scale, shift, dis, rt);
    s12_gmm_pool<<<2048, 256, 0, stream>>>(rt, W3, b3, dis, cursor, csr_src,
                                           batch, poolsum, flags);

    // head
    s12_head<<<N_GRAPH, 64, 0, stream>>>(poolsum, cnts, gfeat, Wg, bg, Wp1, bp1, Wp2, bp2,
                                         (float*)d_out, flags);
}

// Round 13
// 648.402 us; speedup vs baseline: 2.4167x; 1.1524x over previous
//
#include <hip/hip_runtime.h>
#include <hip/hip_bf16.h>

#define N_NODES 100000
#define N_EDGES 1200000
#define N_GRAPH 1000
#define F_INN   7
#define HDIM    64
#define GFEAT   10
#define T_OUT   5
#define EPSF    1e-5f
#define NBLK_SCAN ((N_NODES + 255) / 256)   // 391

// flags: [0]=edge wide(int64) [1]=batch wide [2]=1D fp32 [3]=world fp32

__device__ __forceinline__ float ldf(const void* p, int i, int isf32) {
    return isf32 ? ((const float*)p)[i]
                 : __bfloat162float(((const __hip_bfloat16*)p)[i]);
}
__device__ __forceinline__ float b2f(__hip_bfloat16 v) { return __bfloat162float(v); }
__device__ __forceinline__ int ld_src(const int* edge, int e, int wide) {
    return wide ? edge[2 * e] : edge[e];
}
__device__ __forceinline__ int ld_dst(const int* edge, int e, int wide) {
    return wide ? edge[2 * (N_EDGES + e)] : edge[N_EDGES + e];
}
__device__ __forceinline__ int ld_batch(const int* batch, int v, int wide) {
    return wide ? batch[2 * v] : batch[v];
}

__global__ void SimpleGCN_6640019440134_kernel() {}

__global__ void s13_fill(float* out, int n, float val) {
    int i = blockIdx.x * blockDim.x + threadIdx.x;
    if (i < n) out[i] = val;
}

__global__ void __launch_bounds__(256) s13_probe(const int* edge, const int* batch,
                                                 const unsigned* g1,
                                                 const unsigned short* x,
                                                 const unsigned short* W1,
                                                 const unsigned short* W2,
                                                 int* flags) {
    __shared__ int sh[8];
    int t = threadIdx.x;
    if (t < 8) sh[t] = 0;
    __syncthreads();
    { int pos = 1 + 2 * 4687 * t; if (edge[pos] != 0) atomicOr(&sh[0], 1); }
    { int pos = (N_NODES - 511) + 2 * t; if (batch[pos] != 0) atomicOr(&sh[1], 1); }
    if (t < 16 && g1[t] != 0x3F800000u) atomicOr(&sh[2], 1);
    {
        int e = (x[t] >> 7) & 0xFF;  if (e >= 100 && e <= 140) atomicAdd(&sh[3], 1);
        e = (W1[t] >> 7) & 0xFF;     if (e >= 100 && e <= 140) atomicAdd(&sh[4], 1);
        e = (W2[t] >> 7) & 0xFF;     if (e >= 100 && e <= 140) atomicAdd(&sh[5], 1);
    }
    __syncthreads();
    if (t == 0) {
        flags[0] = (sh[0] == 0);
        flags[1] = (sh[1] == 0);
        flags[2] = (sh[2] == 0);
        int fx = (sh[3] < 192), fw1 = (sh[4] < 192), fw2 = (sh[5] < 192);
        flags[3] = (fx + fw1 + fw2 >= 2);
    }
}

__global__ void s13_zero(int* zbuf, int zcount) {
    int i = blockIdx.x * blockDim.x + threadIdx.x;
    if (i < zcount) zbuf[i] = 0;
}

__global__ void s13_deg(const int* __restrict__ edge, int* degi, const int* __restrict__ fl) {
    int wide = fl[0];
    int e = blockIdx.x * blockDim.x + threadIdx.x;
    if (e < N_EDGES) {
        unsigned d = (unsigned)ld_dst(edge, e, wide);
        if (d < N_NODES) atomicAdd(&degi[d], 1);
    }
}

__global__ void __launch_bounds__(256) s13_scan1(const int* __restrict__ degi,
                                                 int* __restrict__ cursor, int* __restrict__ bsum) {
    __shared__ int tmp[256];
    int i = blockIdx.x * 256 + threadIdx.x;
    int v = (i < N_NODES) ? degi[i] : 0;
    tmp[threadIdx.x] = v;
    __syncthreads();
    for (int o = 1; o < 256; o <<= 1) {
        int t = (threadIdx.x >= o) ? tmp[threadIdx.x - o] : 0;
        __syncthreads();
        tmp[threadIdx.x] += t;
        __syncthreads();
    }
    if (i < N_NODES) cursor[i] = tmp[threadIdx.x] - v;
    if (threadIdx.x == 255) bsum[blockIdx.x] = tmp[255];
}

__global__ void __launch_bounds__(512) s13_scan2(int* bsum) {
    __shared__ int tmp[512];
    int t = threadIdx.x;
    int v = (t < NBLK_SCAN) ? bsum[t] : 0;
    tmp[t] = v;
    __syncthreads();
    for (int o = 1; o < 512; o <<= 1) {
        int a = (t >= o) ? tmp[t - o] : 0;
        __syncthreads();
        tmp[t] += a;
        __syncthreads();
    }
    if (t < NBLK_SCAN) bsum[t] = tmp[t] - v;
}

// scan finalize + dis + per-graph counts (merged)
__global__ void __launch_bounds__(256) s13_scan3_dis(int* cursor, const int* __restrict__ bsum,
                                                     const int* __restrict__ degi, float* dis,
                                                     const int* __restrict__ batch, float* cnts,
                                                     const int* __restrict__ fl) {
    int wide = fl[1];
    int i = blockIdx.x * 256 + threadIdx.x;
    if (i < N_NODES) {
        cursor[i] += bsum[blockIdx.x];
        dis[i] = rsqrtf((float)degi[i] + 1.0f);
        unsigned g = (unsigned)ld_batch(batch, i, wide);
        if (g < N_GRAPH) atomicAdd(&cnts[g], 1.0f);
    }
}

__global__ void s13_csrfill(const int* __restrict__ edge, int* cursor,
                            int* __restrict__ csr_src, const int* __restrict__ fl) {
    int wide = fl[0];
    int e = blockIdx.x * blockDim.x + threadIdx.x;
    if (e < N_EDGES) {
        unsigned s = (unsigned)ld_src(edge, e, wide);
        unsigned d = (unsigned)ld_dst(edge, e, wide);
        if (s < N_NODES && d < N_NODES) {
            int slot = atomicAdd(&cursor[d], 1);
            csr_src[slot] = (int)s;
        }
    }
}

// x̃[v*8+c] = bf16(x[v,c]*dis[v])
__global__ void s13_xprep(const void* x, const float* __restrict__ dis,
                          __hip_bfloat16* __restrict__ xt, const int* __restrict__ fl) {
    int fw = fl[3];
    int i = blockIdx.x * blockDim.x + threadIdx.x;
    if (i < N_NODES * 8) {
        int v = i >> 3, c = i & 7;
        float val = (c < F_INN) ? ldf(x, v * F_INN + c, fw) * dis[v] : 0.f;
        xt[i] = __float2bfloat16(val);
    }
}

// layer 1: agg x̃ (8ch), *dis[v], @W1+b1, BN stats — no in-loop barriers
__global__ void __launch_bounds__(256) s13_g7_mm_bn(const __hip_bfloat16* __restrict__ xt,
                                                    const void* W1, const void* b1,
                                                    const float* __restrict__ dis,
                                                    const int* __restrict__ cursor,
                                                    const int* __restrict__ csr,
                                                    float* __restrict__ bufB,
                                                    float* sums, float* sumsq,
                                                    const int* __restrict__ fl) {
    int fw = fl[3], f1d = fl[2];
    __shared__ float w[F_INN][HDIM];
    __shared__ float shs[4][HDIM], shs2[4][HDIM];
    int t = threadIdx.x, lane = t & 63, sub = t >> 6;
    for (int i = t; i < F_INN * HDIM; i += 256) w[i / HDIM][i % HDIM] = ldf(W1, i, fw);
    __syncthreads();
    float bb = ldf(b1, lane, f1d);
    float s1 = 0.f, s2 = 0.f;
    for (int v = blockIdx.x * 4 + sub; v < N_NODES; v += gridDim.x * 4) {
        int end = cursor[v];
        int start = (v == 0) ? 0 : cursor[v - 1];
        float aggc = (lane < 8) ? b2f(xt[v * 8 + lane]) : 0.f;
        int j = start;
        for (; j + 7 < end; j += 8) {
            int e0 = csr[j], e1 = csr[j+1], e2 = csr[j+2], e3 = csr[j+3];
            int e4 = csr[j+4], e5 = csr[j+5], e6 = csr[j+6], e7 = csr[j+7];
            if (lane < 8) {
                float a0 = b2f(xt[e0*8+lane]), a1 = b2f(xt[e1*8+lane]);
                float a2 = b2f(xt[e2*8+lane]), a3 = b2f(xt[e3*8+lane]);
                float a4 = b2f(xt[e4*8+lane]), a5 = b2f(xt[e5*8+lane]);
                float a6 = b2f(xt[e6*8+lane]), a7 = b2f(xt[e7*8+lane]);
                aggc += ((a0+a1)+(a2+a3)) + ((a4+a5)+(a6+a7));
            }
        }
        for (; j < end; j++) {
            int s = csr[j];
            if (lane < 8) aggc += b2f(xt[s * 8 + lane]);
        }
        aggc *= dis[v];
        float acc = bb;
#pragma unroll
        for (int c = 0; c < F_INN; c++) acc += __shfl(aggc, c) * w[c][lane];
        bufB[v * HDIM + lane] = acc;
        s1 += acc; s2 += acc * acc;
    }
    shs[sub][lane] = s1; shs2[sub][lane] = s2;
    __syncthreads();
    if (sub == 0) {
        float ts  = shs[0][lane] + shs[1][lane] + shs[2][lane] + shs[3][lane];
        float ts2 = shs2[0][lane] + shs2[1][lane] + shs2[2][lane] + shs2[3][lane];
        atomicAdd(&sums[lane], ts);
        atomicAdd(&sumsq[lane], ts2);
    }
}

__global__ void s13_bn_final(float* sums, float* sumsq, const void* gamma, const void* beta,
                             float* scale, float* shift, const int* __restrict__ fl) {
    int f1d = fl[2];
    int j = threadIdx.x;
    float mean = sums[j] / (float)N_NODES;
    float var  = sumsq[j] / (float)N_NODES - mean * mean;
    float sc = ldf(gamma, j, f1d) * rsqrtf(var + EPSF);
    scale[j] = sc;
    shift[j] = ldf(beta, j, f1d) - mean * sc;
    sums[j] = 0.f; sumsq[j] = 0.f;
}

// r̃[v,c] = bf16(relu(bufB*sc+sh) * dis[v])
__global__ void s13_prep(const float* __restrict__ bufB,
                         const float* __restrict__ scale, const float* __restrict__ shift,
                         const float* __restrict__ dis, __hip_bfloat16* __restrict__ rt) {
    int i = blockIdx.x * blockDim.x + threadIdx.x;
    if (i < N_NODES * HDIM) {
        int v = i >> 6, c = i & 63;
        float r = fmaxf(bufB[i] * scale[c] + shift[c], 0.f) * dis[v];
        rt[i] = __float2bfloat16(r);
    }
}

// layer 2: agg r̃ (64ch), *dis[v], @W+b, BN stats — wave-private LDS rows, NO in-loop barrier
__global__ void __launch_bounds__(256) s13_gmm_bn(const __hip_bfloat16* __restrict__ rt,
                                                  const void* W, const void* b,
                                                  const float* __restrict__ dis,
                                                  const int* __restrict__ cursor,
                                                  const int* __restrict__ csr,
                                                  float* __restrict__ bufB,
                                                  float* sums, float* sumsq,
                                                  const int* __restrict__ fl) {
    int fw = fl[3], f1d = fl[2];
    __shared__ float w[HDIM][HDIM];
    __shared__ float rows[4][HDIM];          // rows[sub] is wave-private
    __shared__ float shs[4][HDIM], shs2[4][HDIM];
    int t = threadIdx.x, lane = t & 63, sub = t >> 6;
    for (int i = t; i < HDIM * HDIM; i += 256) w[i / HDIM][i % HDIM] = ldf(W, i, fw);
    __syncthreads();
    float bb = ldf(b, lane, f1d);
    float s1 = 0.f, s2 = 0.f;
    for (int v = blockIdx.x * 4 + sub; v < N_NODES; v += gridDim.x * 4) {
        int end = cursor[v];
        int start = (v == 0) ? 0 : cursor[v - 1];
        float acc = b2f(rt[v * HDIM + lane]);
        int j = start;
        for (; j + 7 < end; j += 8) {
            int e0 = csr[j], e1 = csr[j+1], e2 = csr[j+2], e3 = csr[j+3];
            int e4 = csr[j+4], e5 = csr[j+5], e6 = csr[j+6], e7 = csr[j+7];
            float a0 = b2f(rt[e0*HDIM+lane]), a1 = b2f(rt[e1*HDIM+lane]);
            float a2 = b2f(rt[e2*HDIM+lane]), a3 = b2f(rt[e3*HDIM+lane]);
            float a4 = b2f(rt[e4*HDIM+lane]), a5 = b2f(rt[e5*HDIM+lane]);
            float a6 = b2f(rt[e6*HDIM+lane]), a7 = b2f(rt[e7*HDIM+lane]);
            acc += ((a0+a1)+(a2+a3)) + ((a4+a5)+(a6+a7));
        }
        for (; j < end; j++) acc += b2f(rt[csr[j] * HDIM + lane]);
        acc *= dis[v];
        rows[sub][lane] = acc;               // intra-wave LDS, lockstep-safe
        float val = bb;
#pragma unroll
        for (int k = 0; k < HDIM; k++) val += rows[sub][k] * w[k][lane];
        bufB[v * HDIM + lane] = val;
        s1 += val; s2 += val * val;
    }
    shs[sub][lane] = s1; shs2[sub][lane] = s2;
    __syncthreads();
    if (sub == 0) {
        float ts  = shs[0][lane] + shs[1][lane] + shs[2][lane] + shs[3][lane];
        float ts2 = shs2[0][lane] + shs2[1][lane] + shs2[2][lane] + shs2[3][lane];
        atomicAdd(&sums[lane], ts);
        atomicAdd(&sumsq[lane], ts2);
    }
}

// layer 3: agg r̃, *dis[v], @W3+b3, pool — no in-loop barrier
__global__ void __launch_bounds__(256) s13_gmm_pool(const __hip_bfloat16* __restrict__ rt,
                                                    const void* W3, const void* b3,
                                                    const float* __restrict__ dis,
                                                    const int* __restrict__ cursor,
                                                    const int* __restrict__ csr,
                                                    const int* __restrict__ batch,
                                                    float* __restrict__ poolsum,
                                                    const int* __restrict__ fl) {
    int fw = fl[3], f1d = fl[2], wide = fl[1];
    __shared__ float w[HDIM][HDIM];
    __shared__ float rows[4][HDIM];
    int t = threadIdx.x, lane = t & 63, sub = t >> 6;
    for (int i = t; i < HDIM * HDIM; i += 256) w[i / HDIM][i % HDIM] = ldf(W3, i, fw);
    __syncthreads();
    float bb = ldf(b3, lane, f1d);
    for (int v = blockIdx.x * 4 + sub; v < N_NODES; v += gridDim.x * 4) {
        int end = cursor[v];
        int start = (v == 0) ? 0 : cursor[v - 1];
        float acc = b2f(rt[v * HDIM + lane]);
        int j = start;
        for (; j + 7 < end; j += 8) {
            int e0 = csr[j], e1 = csr[j+1], e2 = csr[j+2], e3 = csr[j+3];
            int e4 = csr[j+4], e5 = csr[j+5], e6 = csr[j+6], e7 = csr[j+7];
            float a0 = b2f(rt[e0*HDIM+lane]), a1 = b2f(rt[e1*HDIM+lane]);
            float a2 = b2f(rt[e2*HDIM+lane]), a3 = b2f(rt[e3*HDIM+lane]);
            float a4 = b2f(rt[e4*HDIM+lane]), a5 = b2f(rt[e5*HDIM+lane]);
            float a6 = b2f(rt[e6*HDIM+lane]), a7 = b2f(rt[e7*HDIM+lane]);
            acc += ((a0+a1)+(a2+a3)) + ((a4+a5)+(a6+a7));
        }
        for (; j < end; j++) acc += b2f(rt[csr[j] * HDIM + lane]);
        acc *= dis[v];
        rows[sub][lane] = acc;
        float val = bb;
#pragma unroll
        for (int k = 0; k < HDIM; k++) val += rows[sub][k] * w[k][lane];
        unsigned g = (unsigned)ld_batch(batch, v, wide);
        if (g < N_GRAPH) atomicAdd(&poolsum[g * HDIM + lane], val);
    }
}

__global__ void __launch_bounds__(64) s13_head(const float* __restrict__ poolsum,
                                               const float* __restrict__ cnts,
                                               const void* gfeat, const void* Wg, const void* bg,
                                               const void* Wp1, const void* bp1,
                                               const void* Wp2, const void* bp2,
                                               float* __restrict__ out,
                                               const int* __restrict__ fl) {
    int f1d = fl[2], fw = fl[3];
    int g = blockIdx.x, t = threadIdx.x;
    __shared__ float comb[HDIM + HDIM / 2];
    __shared__ float hid[HDIM];
    float cnt = fmaxf(cnts[g], 1.0f);
    comb[t] = poolsum[g * HDIM + t] / cnt;
    if (t < HDIM / 2) {
        float a = ldf(bg, t, f1d);
#pragma unroll
        for (int k = 0; k < GFEAT; k++)
            a += ldf(gfeat, g * GFEAT + k, fw) * ldf(Wg, k * (HDIM / 2) + t, fw);
        comb[HDIM + t] = fmaxf(a, 0.f);
    }
    __syncthreads();
    float a = ldf(bp1, t, f1d);
    for (int k = 0; k < HDIM + HDIM / 2; k++) a += comb[k] * ldf(Wp1, k * HDIM + t, fw);
    hid[t] = fmaxf(a, 0.f);
    __syncthreads();
    if (t < T_OUT) {
        float o = ldf(bp2, t, f1d);
#pragma unroll
        for (int k = 0; k < HDIM; k++) o += hid[k] * ldf(Wp2, k * T_OUT + t, fw);
        out[g * T_OUT + t] = o;
    }
}

extern "C" __attribute__((visibility("default")))
void kernel_launch(void* const* d_in, const int* in_sizes, int n_in,
                   void* d_out, int out_size, void* d_ws, size_t ws_size,
                   hipStream_t stream) {
    static const int exp_sizes[20] = {700000, 10000, 448, 64, 4096, 64, 4096, 64,
                                      64, 64, 64, 64, 320, 32, 6144, 64, 320, 5,
                                      2400000, 100000};
    bool ok = (n_in == 20) && (out_size == N_GRAPH * T_OUT);
    if (ok) for (int i = 0; i < 20; i++) ok = ok && (in_sizes[i] == exp_sizes[i]);
    if (!ok) {
        s13_fill<<<(out_size + 255) / 256, 256, 0, stream>>>((float*)d_out, out_size, 900.0f);
        return;
    }

    const void* x      = d_in[0];
    const void* gfeat  = d_in[1];
    const void* W1     = d_in[2];
    const void* b1     = d_in[3];
    const void* W2     = d_in[4];
    const void* b2     = d_in[5];
    const void* W3     = d_in[6];
    const void* b3     = d_in[7];
    const void* gamma1 = d_in[8];
    const void* beta1  = d_in[9];
    const void* gamma2 = d_in[10];
    const void* beta2  = d_in[11];
    const void* Wg     = d_in[12];
    const void* bg     = d_in[13];
    const void* Wp1    = d_in[14];
    const void* bp1    = d_in[15];
    const void* Wp2    = d_in[16];
    const void* bp2    = d_in[17];
    const int* edge  = (const int*)d_in[18];
    const int* batch = (const int*)d_in[19];

    // workspace layout (4-byte words)
    int*   flags   = (int*)d_ws;                        // 16
    int*   degi    = flags + 16;                        // N
    float* dis     = (float*)(degi + N_NODES);          // N
    float* cnts    = dis + N_NODES;                     // G
    float* sums    = cnts + N_GRAPH;                    // H
    float* sumsq   = sums + HDIM;                       // H
    float* scale   = sumsq + HDIM;                      // H
    float* shift   = scale + HDIM;                      // H
    float* poolsum = shift + HDIM;                      // G*H
    int*   cursor  = (int*)(poolsum + N_GRAPH * HDIM);  // N
    int*   bsum    = cursor + N_NODES;                  // 512
    int*   csr_src = bsum + 512;                        // E
    __hip_bfloat16* xt = (__hip_bfloat16*)(csr_src + N_EDGES);  // N*8 bf16
    __hip_bfloat16* rt = xt + (size_t)N_NODES * 8;              // N*64 bf16
    float* bufB    = (float*)(rt + (size_t)N_NODES * HDIM);     // N*H fp32

    const size_t need = (size_t)(16 + 3 * N_NODES + N_GRAPH + 4 * HDIM + N_GRAPH * HDIM
                                 + 512 + N_EDGES + 4 * N_NODES + 32 * N_NODES
                                 + 64 * (size_t)N_NODES) * 4;
    if (ws_size < need) {
        s13_fill<<<(out_size + 255) / 256, 256, 0, stream>>>((float*)d_out, out_size, 500.0f);
        return;
    }

    s13_probe<<<1, 256, 0, stream>>>(edge, batch, (const unsigned*)gamma1,
                                     (const unsigned short*)x, (const unsigned short*)W1,
                                     (const unsigned short*)W2, flags);

    int zcount = 2 * N_NODES + N_GRAPH + 4 * HDIM + N_GRAPH * HDIM;
    s13_zero<<<(zcount + 255) / 256, 256, 0, stream>>>(degi, zcount);

    s13_deg<<<(N_EDGES + 255) / 256, 256, 0, stream>>>(edge, degi, flags);
    s13_scan1<<<NBLK_SCAN, 256, 0, stream>>>(degi, cursor, bsum);
    s13_scan2<<<1, 512, 0, stream>>>(bsum);
    s13_scan3_dis<<<NBLK_SCAN, 256, 0, stream>>>(cursor, bsum, degi, dis, batch, cnts, flags);
    s13_csrfill<<<(N_EDGES + 255) / 256, 256, 0, stream>>>(edge, cursor, csr_src, flags);

    // layer 1
    s13_xprep<<<(N_NODES * 8 + 255) / 256, 256, 0, stream>>>(x, dis, xt, flags);
    s13_g7_mm_bn<<<2048, 256, 0, stream>>>(xt, W1, b1, dis, cursor, csr_src,
                                           bufB, sums, sumsq, flags);
    s13_bn_final<<<1, 64, 0, stream>>>(sums, sumsq, gamma1, beta1, scale, shift, flags);

    // layer 2
    s13_prep<<<(N_NODES * HDIM + 255) / 256, 256, 0, stream>>>(bufB, scale, shift, dis, rt);
    s13_gmm_bn<<<2048, 256, 0, stream>>>(rt, W2, b2, dis, cursor, csr_src,
                                         bufB, sums, sumsq, flags);
    s13_bn_final<<<1, 64, 0, stream>>>(sums, sumsq, gamma2, beta2, scale, shift, flags);

    // layer 3
    s13_prep<<<(N_NODES * HDIM + 255) / 256, 256, 0, stream>>>(bufB, scale, shift, dis, rt);
    s13_gmm_pool<<<2048, 256, 0, stream>>>(rt, W3, b3, dis, cursor, csr_src,
                                           batch, poolsum, flags);

    // head
    s13_head<<<N_GRAPH, 64, 0, stream>>>(poolsum, cnts, gfeat, Wg, bg, Wp1, bp1, Wp2, bp2,
                                         (float*)d_out, flags);
}